// Round 1
// baseline (568.844 us; speedup 1.0000x reference)
//
#include <hip/hip_runtime.h>

#define NU 100000
#define NI 50000
#define NN 150000          // NU + NI
#define HH 64
#define NE 1200000

#define SCAN_CHUNK 1024
#define NBLK ((NN + SCAN_CHUNK - 1) / SCAN_CHUNK)   // 147

// ---------------------------------------------------------------- concat + passthrough
// A[i] = concat(users, items); also writes users_emb/items_emb passthrough outputs.
__global__ void k_concat(const float4* __restrict__ users, const float4* __restrict__ items,
                         float4* __restrict__ A, float4* __restrict__ out) {
    int i = blockIdx.x * blockDim.x + threadIdx.x;   // over NN*16 float4
    const int TOT = NN * (HH / 4);                   // 2,400,000
    const int UB  = NU * (HH / 4);                   // 1,600,000
    if (i >= TOT) return;
    float4 v;
    if (i < UB) {
        v = users[i];
        out[UB + i] = v;                             // O1 = NU*64 floats
    } else {
        int j = i - UB;
        v = items[j];
        out[2 * UB + NI * (HH / 4) + j] = v;         // O3 = (2*NU+NI)*64 floats
    }
    A[i] = v;
}

// ---------------------------------------------------------------- degree histogram
__global__ void k_hist(const int* __restrict__ dst, int* __restrict__ counts) {
    int e = blockIdx.x * blockDim.x + threadIdx.x;
    if (e < NE) atomicAdd(&counts[dst[e]], 1);
}

// dinv[n] = rsqrt(in_degree + 1)   (+1 = self loop; always > 0)
__global__ void k_dinv(const int* __restrict__ counts, float* __restrict__ dinv) {
    int n = blockIdx.x * blockDim.x + threadIdx.x;
    if (n < NN) dinv[n] = rsqrtf((float)(counts[n] + 1));
}

// ---------------------------------------------------------------- exclusive scan (3 kernels)
__global__ void k_scan_reduce(const int* __restrict__ counts, int* __restrict__ bsum) {
    __shared__ int sd[256];
    int t = threadIdx.x;
    int base = blockIdx.x * SCAN_CHUNK + t * 4;
    int s = 0;
    if (base + 3 < NN) {
        int4 v = *(const int4*)(counts + base);
        s = v.x + v.y + v.z + v.w;
    } else {
        for (int i = 0; i < 4; ++i)
            if (base + i < NN) s += counts[base + i];
    }
    sd[t] = s; __syncthreads();
    for (int off = 128; off > 0; off >>= 1) {
        if (t < off) sd[t] += sd[t + off];
        __syncthreads();
    }
    if (t == 0) bsum[blockIdx.x] = sd[0];
}

__global__ void k_scan_top(int* __restrict__ bsum, int* __restrict__ row_ptr) {
    __shared__ int sd[256];
    int t = threadIdx.x;
    int v = (t < NBLK) ? bsum[t] : 0;
    sd[t] = v; __syncthreads();
    for (int off = 1; off < 256; off <<= 1) {
        int x = (t >= off) ? sd[t - off] : 0;
        __syncthreads();
        sd[t] += x;
        __syncthreads();
    }
    if (t < NBLK) bsum[t] = sd[t] - v;   // exclusive block offsets
    if (t == 0) row_ptr[NN] = NE;
}

__global__ void k_scan_chunks(const int* __restrict__ counts, const int* __restrict__ boff,
                              int* __restrict__ row_ptr) {
    __shared__ int sd[256];
    int t = threadIdx.x;
    int base = blockIdx.x * SCAN_CHUNK + t * 4;
    int c[4];
#pragma unroll
    for (int i = 0; i < 4; ++i) c[i] = (base + i < NN) ? counts[base + i] : 0;
    int tt = c[0] + c[1] + c[2] + c[3];
    sd[t] = tt; __syncthreads();
    for (int off = 1; off < 256; off <<= 1) {
        int x = (t >= off) ? sd[t - off] : 0;
        __syncthreads();
        sd[t] += x;
        __syncthreads();
    }
    int off0 = boff[blockIdx.x] + (sd[t] - tt);
    int run = 0;
#pragma unroll
    for (int i = 0; i < 4; ++i) {
        if (base + i < NN) row_ptr[base + i] = off0 + run;
        run += c[i];
    }
}

// ---------------------------------------------------------------- CSR fill: (src, norm) per slot
__global__ void k_fill(const int* __restrict__ src, const int* __restrict__ dst,
                       const float* __restrict__ dinv, const int* __restrict__ row_ptr,
                       int* __restrict__ cursor, int2* __restrict__ colw) {
    int e = blockIdx.x * blockDim.x + threadIdx.x;
    if (e >= NE) return;
    int s = src[e], d = dst[e];
    int pos = row_ptr[d] + atomicAdd(&cursor[d], 1);
    float w = dinv[s] * dinv[d];
    colw[pos] = make_int2(s, __float_as_int(w));
}

// ---------------------------------------------------------------- aggregation: y = A_norm * x
// one wave per node, lane = feature. Self-loop handled analytically.
__global__ void k_aggregate(const float* __restrict__ x, float* __restrict__ y,
                            const float* __restrict__ dinv, const int* __restrict__ row_ptr,
                            const int2* __restrict__ colw) {
    int node = blockIdx.x * 4 + (threadIdx.x >> 6);
    if (node >= NN) return;
    int lane = threadIdx.x & 63;
    float dv = dinv[node];
    float acc = dv * dv * x[node * HH + lane];
    int e = row_ptr[node], end = row_ptr[node + 1];
    for (; e + 1 < end; e += 2) {
        int2 cw0 = colw[e];
        int2 cw1 = colw[e + 1];
        float v0 = x[cw0.x * HH + lane];
        float v1 = x[cw1.x * HH + lane];
        acc += __int_as_float(cw0.y) * v0;
        acc += __int_as_float(cw1.y) * v1;
    }
    if (e < end) {
        int2 cw = colw[e];
        acc += __int_as_float(cw.y) * x[cw.x * HH + lane];
    }
    y[node * HH + lane] = acc;
}

// ---------------------------------------------------------------- GEMM: out = y @ W + b
// 256 threads, 128 rows/block; thread tile 4 rows x 8 cols; W + x-tile in LDS.
// Rows >= `split` go to out_hi at (r - split) — used to write d_out's two x slices.
#define GR 128
#define XSS 65   // +1 pad: conflict-free scalar broadcasts
__global__ __launch_bounds__(256) void k_gemm(const float* __restrict__ y,
                                              const float* __restrict__ W,
                                              const float* __restrict__ b,
                                              float* __restrict__ out_lo,
                                              float* __restrict__ out_hi,
                                              int split) {
    __shared__ float xs[GR * XSS];   // 33.3 KB
    __shared__ float ws[HH * HH];    // 16 KB
    int t = threadIdx.x;
    int rowBase = blockIdx.x * GR;

    {   // stage W: 1024 float4 / 256 threads
        const float4* W4 = (const float4*)W;
        float4* ws4 = (float4*)ws;
#pragma unroll
        for (int i = 0; i < 4; ++i) ws4[i * 256 + t] = W4[i * 256 + t];
    }
    // stage x tile: 2048 float4 / 256 threads
#pragma unroll
    for (int it = 0; it < 8; ++it) {
        int g = it * 256 + t;        // 0..2047
        int r = g >> 4;
        int c0 = (g & 15) << 2;
        if (rowBase + r < NN) {
            float4 v = *(const float4*)(y + (size_t)(rowBase + r) * HH + c0);
            xs[r * XSS + c0 + 0] = v.x;
            xs[r * XSS + c0 + 1] = v.y;
            xs[r * XSS + c0 + 2] = v.z;
            xs[r * XSS + c0 + 3] = v.w;
        }
    }
    __syncthreads();

    int tx = t & 7;        // 8 col-groups of 8
    int ty = t >> 3;       // 32 row-groups of 4
    int j0 = tx * 8;
    int r0 = ty * 4;

    float acc[4][8];
#pragma unroll
    for (int i = 0; i < 4; ++i)
#pragma unroll
        for (int j = 0; j < 8; ++j) acc[i][j] = 0.f;

    for (int k = 0; k < HH; ++k) {
        float4 w0 = *(const float4*)(ws + k * HH + j0);
        float4 w1 = *(const float4*)(ws + k * HH + j0 + 4);
        float wv[8] = {w0.x, w0.y, w0.z, w0.w, w1.x, w1.y, w1.z, w1.w};
#pragma unroll
        for (int i = 0; i < 4; ++i) {
            float xv = xs[(r0 + i) * XSS + k];
#pragma unroll
            for (int j = 0; j < 8; ++j) acc[i][j] += xv * wv[j];
        }
    }

    float bj[8];
#pragma unroll
    for (int j = 0; j < 8; ++j) bj[j] = b[j0 + j];

#pragma unroll
    for (int i = 0; i < 4; ++i) {
        int r = rowBase + r0 + i;
        if (r >= NN) continue;
        float4 o0 = make_float4(acc[i][0] + bj[0], acc[i][1] + bj[1],
                                acc[i][2] + bj[2], acc[i][3] + bj[3]);
        float4 o1 = make_float4(acc[i][4] + bj[4], acc[i][5] + bj[5],
                                acc[i][6] + bj[6], acc[i][7] + bj[7]);
        float* d = (r < split) ? (out_lo + (size_t)r * HH)
                               : (out_hi + (size_t)(r - split) * HH);
        *(float4*)(d + j0) = o0;
        *(float4*)(d + j0 + 4) = o1;
    }
}

// ---------------------------------------------------------------- launch
extern "C" void kernel_launch(void* const* d_in, const int* in_sizes, int n_in,
                              void* d_out, int out_size, void* d_ws, size_t ws_size,
                              hipStream_t stream) {
    const int*   edge  = (const int*)d_in[0];
    const int*   src   = edge;           // edge_index[0]
    const int*   dst   = edge + NE;      // edge_index[1]
    const float* users = (const float*)d_in[1];
    const float* items = (const float*)d_in[2];
    const float* Ws    = (const float*)d_in[3];   // [3][64][64]
    const float* bs    = (const float*)d_in[4];   // [3][64]
    float*       out   = (float*)d_out;

    // workspace carve (~89 MB total)
    char* w = (char*)d_ws;
    float* A       = (float*)w; w += (size_t)NN * HH * 4;   // 38.4 MB
    float* B       = (float*)w; w += (size_t)NN * HH * 4;   // 38.4 MB
    float* dinv    = (float*)w; w += (size_t)NN * 4;
    int*   counts  = (int*)w;   w += (size_t)NN * 4;
    int*   cursor  = (int*)w;   w += (size_t)NN * 4;        // adjacent to counts: one memset
    int*   row_ptr = (int*)w;   w += (size_t)(NN + 1) * 4;
    w += 4;                                                 // 8-byte align
    int*   bsum    = (int*)w;   w += 256 * 4;
    int2*  colw    = (int2*)w;  w += (size_t)NE * 8;        // 9.6 MB
    (void)ws_size; (void)in_sizes; (void)n_in; (void)out_size;

    hipMemsetAsync(counts, 0, (size_t)2 * NN * sizeof(int), stream);  // counts + cursor

    k_concat<<<(NN * (HH / 4) + 255) / 256, 256, 0, stream>>>(
        (const float4*)users, (const float4*)items, (float4*)A, (float4*)out);

    k_hist<<<(NE + 255) / 256, 256, 0, stream>>>(dst, counts);
    k_dinv<<<(NN + 255) / 256, 256, 0, stream>>>(counts, dinv);
    k_scan_reduce<<<NBLK, 256, 0, stream>>>(counts, bsum);
    k_scan_top<<<1, 256, 0, stream>>>(bsum, row_ptr);
    k_scan_chunks<<<NBLK, 256, 0, stream>>>(counts, bsum, row_ptr);
    k_fill<<<(NE + 255) / 256, 256, 0, stream>>>(src, dst, dinv, row_ptr, cursor, colw);

    for (int l = 0; l < 3; ++l) {
        k_aggregate<<<(NN + 3) / 4, 256, 0, stream>>>(A, B, dinv, row_ptr, colw);
        if (l < 2) {
            k_gemm<<<(NN + GR - 1) / GR, 256, 0, stream>>>(
                B, Ws + l * HH * HH, bs + l * HH, A, A, NN);
        } else {
            // final layer: write straight into d_out's two x slices
            k_gemm<<<(NN + GR - 1) / GR, 256, 0, stream>>>(
                B, Ws + l * HH * HH, bs + l * HH,
                out /* x_users at offset 0 */,
                out + (size_t)2 * NU * HH /* x_items */, NU);
        }
    }
}

// Round 2
// 500.789 us; speedup vs baseline: 1.1359x; 1.1359x over previous
//
#include <hip/hip_runtime.h>
#include <hip/hip_fp16.h>
#include <type_traits>

#define NU 100000
#define NI 50000
#define NN 150000          // NU + NI
#define HH 64
#define NE 1200000

#define SCAN_CHUNK 1024
#define NBLK ((NN + SCAN_CHUNK - 1) / SCAN_CHUNK)   // 147

// ---------------------------------------------------------------- concat + passthrough
// Writes fp16 gather-source Ah = concat(users, items), plus fp32 passthrough outputs.
__global__ void k_concat(const float4* __restrict__ users, const float4* __restrict__ items,
                         __half2* __restrict__ Ah, float4* __restrict__ out) {
    int i = blockIdx.x * blockDim.x + threadIdx.x;   // over NN*16 float4
    const int TOT = NN * (HH / 4);                   // 2,400,000
    const int UB  = NU * (HH / 4);                   // 1,600,000
    if (i >= TOT) return;
    float4 v;
    if (i < UB) {
        v = users[i];
        out[UB + i] = v;                             // O1 = users_emb passthrough
    } else {
        int j = i - UB;
        v = items[j];
        out[2 * UB + NI * (HH / 4) + j] = v;         // O3 = items_emb passthrough
    }
    Ah[2 * i]     = __halves2half2(__float2half_rn(v.x), __float2half_rn(v.y));
    Ah[2 * i + 1] = __halves2half2(__float2half_rn(v.z), __float2half_rn(v.w));
}

// ---------------------------------------------------------------- degree histogram
__global__ void k_hist(const int* __restrict__ dst, int* __restrict__ counts) {
    int e = blockIdx.x * blockDim.x + threadIdx.x;
    if (e < NE) atomicAdd(&counts[dst[e]], 1);
}

// dinv[n] = rsqrt(in_degree + 1)   (+1 = self loop; always > 0)
__global__ void k_dinv(const int* __restrict__ counts, float* __restrict__ dinv) {
    int n = blockIdx.x * blockDim.x + threadIdx.x;
    if (n < NN) dinv[n] = rsqrtf((float)(counts[n] + 1));
}

// ---------------------------------------------------------------- exclusive scan (3 kernels)
__global__ void k_scan_reduce(const int* __restrict__ counts, int* __restrict__ bsum) {
    __shared__ int sd[256];
    int t = threadIdx.x;
    int base = blockIdx.x * SCAN_CHUNK + t * 4;
    int s = 0;
    if (base + 3 < NN) {
        int4 v = *(const int4*)(counts + base);
        s = v.x + v.y + v.z + v.w;
    } else {
        for (int i = 0; i < 4; ++i)
            if (base + i < NN) s += counts[base + i];
    }
    sd[t] = s; __syncthreads();
    for (int off = 128; off > 0; off >>= 1) {
        if (t < off) sd[t] += sd[t + off];
        __syncthreads();
    }
    if (t == 0) bsum[blockIdx.x] = sd[0];
}

__global__ void k_scan_top(int* __restrict__ bsum, int* __restrict__ row_ptr) {
    __shared__ int sd[256];
    int t = threadIdx.x;
    int v = (t < NBLK) ? bsum[t] : 0;
    sd[t] = v; __syncthreads();
    for (int off = 1; off < 256; off <<= 1) {
        int x = (t >= off) ? sd[t - off] : 0;
        __syncthreads();
        sd[t] += x;
        __syncthreads();
    }
    if (t < NBLK) bsum[t] = sd[t] - v;   // exclusive block offsets
    if (t == 0) row_ptr[NN] = NE;
}

__global__ void k_scan_chunks(const int* __restrict__ counts, const int* __restrict__ boff,
                              int* __restrict__ row_ptr) {
    __shared__ int sd[256];
    int t = threadIdx.x;
    int base = blockIdx.x * SCAN_CHUNK + t * 4;
    int c[4];
#pragma unroll
    for (int i = 0; i < 4; ++i) c[i] = (base + i < NN) ? counts[base + i] : 0;
    int tt = c[0] + c[1] + c[2] + c[3];
    sd[t] = tt; __syncthreads();
    for (int off = 1; off < 256; off <<= 1) {
        int x = (t >= off) ? sd[t - off] : 0;
        __syncthreads();
        sd[t] += x;
        __syncthreads();
    }
    int off0 = boff[blockIdx.x] + (sd[t] - tt);
    int run = 0;
#pragma unroll
    for (int i = 0; i < 4; ++i) {
        if (base + i < NN) row_ptr[base + i] = off0 + run;
        run += c[i];
    }
}

// ---------------------------------------------------------------- CSR fill: (src, norm) per slot
__global__ void k_fill(const int* __restrict__ src, const int* __restrict__ dst,
                       const float* __restrict__ dinv, const int* __restrict__ row_ptr,
                       int* __restrict__ cursor, int2* __restrict__ colw) {
    int e = blockIdx.x * blockDim.x + threadIdx.x;
    if (e >= NE) return;
    int s = src[e], d = dst[e];
    int pos = row_ptr[d] + atomicAdd(&cursor[d], 1);
    float w = dinv[s] * dinv[d];
    colw[pos] = make_int2(s, __float_as_int(w));
}

// ---------------------------------------------------------------- aggregation: y = A_norm * x
// one wave per node, lane = feature. fp16 gather source, fp32 accumulate.
// 4-deep unroll: 4 independent colw loads then 4 independent row gathers in flight.
__global__ void k_aggregate(const __half* __restrict__ x, float* __restrict__ y,
                            const float* __restrict__ dinv, const int* __restrict__ row_ptr,
                            const int2* __restrict__ colw) {
    int node = blockIdx.x * 4 + (threadIdx.x >> 6);
    if (node >= NN) return;
    int lane = threadIdx.x & 63;
    float dv = dinv[node];
    float acc = dv * dv * __half2float(x[node * HH + lane]);
    int e = row_ptr[node], end = row_ptr[node + 1];
    for (; e + 3 < end; e += 4) {
        int2 c0 = colw[e];
        int2 c1 = colw[e + 1];
        int2 c2 = colw[e + 2];
        int2 c3 = colw[e + 3];
        float v0 = __half2float(x[c0.x * HH + lane]);
        float v1 = __half2float(x[c1.x * HH + lane]);
        float v2 = __half2float(x[c2.x * HH + lane]);
        float v3 = __half2float(x[c3.x * HH + lane]);
        acc += __int_as_float(c0.y) * v0;
        acc += __int_as_float(c1.y) * v1;
        acc += __int_as_float(c2.y) * v2;
        acc += __int_as_float(c3.y) * v3;
    }
    if (e + 1 < end) {
        int2 c0 = colw[e];
        int2 c1 = colw[e + 1];
        float v0 = __half2float(x[c0.x * HH + lane]);
        float v1 = __half2float(x[c1.x * HH + lane]);
        acc += __int_as_float(c0.y) * v0;
        acc += __int_as_float(c1.y) * v1;
        e += 2;
    }
    if (e < end) {
        int2 c = colw[e];
        acc += __int_as_float(c.y) * __half2float(x[c.x * HH + lane]);
    }
    y[node * HH + lane] = acc;
}

// ---------------------------------------------------------------- GEMM: out = y @ W + b
// 256 threads, 128 rows/block; thread tile 4 rows x 8 cols; W + x-tile in LDS.
// OutT=float: split-write into d_out's two x slices. OutT=__half: fp16 gather
// source for the next layer's aggregation.
#define GR 128
#define XSS 65   // +1 pad: conflict-free scalar broadcasts
template <typename OutT>
__global__ __launch_bounds__(256) void k_gemm(const float* __restrict__ y,
                                              const float* __restrict__ W,
                                              const float* __restrict__ b,
                                              OutT* __restrict__ out_lo,
                                              OutT* __restrict__ out_hi,
                                              int split) {
    __shared__ float xs[GR * XSS];   // 33.3 KB
    __shared__ float ws[HH * HH];    // 16 KB
    int t = threadIdx.x;
    int rowBase = blockIdx.x * GR;

    {   // stage W: 1024 float4 / 256 threads
        const float4* W4 = (const float4*)W;
        float4* ws4 = (float4*)ws;
#pragma unroll
        for (int i = 0; i < 4; ++i) ws4[i * 256 + t] = W4[i * 256 + t];
    }
    // stage x tile: 2048 float4 / 256 threads
#pragma unroll
    for (int it = 0; it < 8; ++it) {
        int g = it * 256 + t;        // 0..2047
        int r = g >> 4;
        int c0 = (g & 15) << 2;
        if (rowBase + r < NN) {
            float4 v = *(const float4*)(y + (size_t)(rowBase + r) * HH + c0);
            xs[r * XSS + c0 + 0] = v.x;
            xs[r * XSS + c0 + 1] = v.y;
            xs[r * XSS + c0 + 2] = v.z;
            xs[r * XSS + c0 + 3] = v.w;
        }
    }
    __syncthreads();

    int tx = t & 7;        // 8 col-groups of 8
    int ty = t >> 3;       // 32 row-groups of 4
    int j0 = tx * 8;
    int r0 = ty * 4;

    float acc[4][8];
#pragma unroll
    for (int i = 0; i < 4; ++i)
#pragma unroll
        for (int j = 0; j < 8; ++j) acc[i][j] = 0.f;

    for (int k = 0; k < HH; ++k) {
        float4 w0 = *(const float4*)(ws + k * HH + j0);
        float4 w1 = *(const float4*)(ws + k * HH + j0 + 4);
        float wv[8] = {w0.x, w0.y, w0.z, w0.w, w1.x, w1.y, w1.z, w1.w};
#pragma unroll
        for (int i = 0; i < 4; ++i) {
            float xv = xs[(r0 + i) * XSS + k];
#pragma unroll
            for (int j = 0; j < 8; ++j) acc[i][j] += xv * wv[j];
        }
    }

    float bj[8];
#pragma unroll
    for (int j = 0; j < 8; ++j) bj[j] = b[j0 + j];

#pragma unroll
    for (int i = 0; i < 4; ++i) {
        int r = rowBase + r0 + i;
        if (r >= NN) continue;
        if constexpr (std::is_same_v<OutT, float>) {
            float4 o0 = make_float4(acc[i][0] + bj[0], acc[i][1] + bj[1],
                                    acc[i][2] + bj[2], acc[i][3] + bj[3]);
            float4 o1 = make_float4(acc[i][4] + bj[4], acc[i][5] + bj[5],
                                    acc[i][6] + bj[6], acc[i][7] + bj[7]);
            float* d = (r < split) ? ((float*)out_lo + (size_t)r * HH)
                                   : ((float*)out_hi + (size_t)(r - split) * HH);
            *(float4*)(d + j0) = o0;
            *(float4*)(d + j0 + 4) = o1;
        } else {
            __half2 h[4];
#pragma unroll
            for (int j = 0; j < 4; ++j)
                h[j] = __halves2half2(__float2half_rn(acc[i][2 * j] + bj[2 * j]),
                                      __float2half_rn(acc[i][2 * j + 1] + bj[2 * j + 1]));
            __half* d = (__half*)out_lo + (size_t)r * HH + j0;
            *(int4*)d = *(int4*)h;   // 8 halves = 16 B, j0*2 is 16-B aligned
        }
    }
}

// ---------------------------------------------------------------- launch
extern "C" void kernel_launch(void* const* d_in, const int* in_sizes, int n_in,
                              void* d_out, int out_size, void* d_ws, size_t ws_size,
                              hipStream_t stream) {
    const int*   edge  = (const int*)d_in[0];
    const int*   src   = edge;           // edge_index[0]
    const int*   dst   = edge + NE;      // edge_index[1]
    const float* users = (const float*)d_in[1];
    const float* items = (const float*)d_in[2];
    const float* Ws    = (const float*)d_in[3];   // [3][64][64]
    const float* bs    = (const float*)d_in[4];   // [3][64]
    float*       out   = (float*)d_out;

    // workspace carve (~70 MB total)
    char* w = (char*)d_ws;
    float*  B       = (float*)w;  w += (size_t)NN * HH * 4;   // 38.4 MB (aggregate out, fp32)
    __half* Ah      = (__half*)w; w += (size_t)NN * HH * 2;   // 19.2 MB (gather source, fp16)
    float*  dinv    = (float*)w;  w += (size_t)NN * 4;
    int*    counts  = (int*)w;    w += (size_t)NN * 4;
    int*    cursor  = (int*)w;    w += (size_t)NN * 4;        // adjacent to counts: one memset
    int*    row_ptr = (int*)w;    w += (size_t)(NN + 1) * 4;
    w += 4;                                                   // 8-byte align
    int*    bsum    = (int*)w;    w += 256 * 4;
    int2*   colw    = (int2*)w;   w += (size_t)NE * 8;        // 9.6 MB
    (void)ws_size; (void)in_sizes; (void)n_in; (void)out_size;

    hipMemsetAsync(counts, 0, (size_t)2 * NN * sizeof(int), stream);  // counts + cursor

    k_concat<<<(NN * (HH / 4) + 255) / 256, 256, 0, stream>>>(
        (const float4*)users, (const float4*)items, (__half2*)Ah, (float4*)out);

    k_hist<<<(NE + 255) / 256, 256, 0, stream>>>(dst, counts);
    k_dinv<<<(NN + 255) / 256, 256, 0, stream>>>(counts, dinv);
    k_scan_reduce<<<NBLK, 256, 0, stream>>>(counts, bsum);
    k_scan_top<<<1, 256, 0, stream>>>(bsum, row_ptr);
    k_scan_chunks<<<NBLK, 256, 0, stream>>>(counts, bsum, row_ptr);
    k_fill<<<(NE + 255) / 256, 256, 0, stream>>>(src, dst, dinv, row_ptr, cursor, colw);

    for (int l = 0; l < 3; ++l) {
        k_aggregate<<<(NN + 3) / 4, 256, 0, stream>>>(Ah, B, dinv, row_ptr, colw);
        if (l < 2) {
            k_gemm<__half><<<(NN + GR - 1) / GR, 256, 0, stream>>>(
                B, Ws + l * HH * HH, bs + l * HH, Ah, Ah, NN);
        } else {
            // final layer: write straight into d_out's two x slices
            k_gemm<float><<<(NN + GR - 1) / GR, 256, 0, stream>>>(
                B, Ws + l * HH * HH, bs + l * HH,
                out /* x_users at offset 0 */,
                out + (size_t)2 * NU * HH /* x_items */, NU);
        }
    }
}